// Round 5
// baseline (230.010 us; speedup 1.0000x reference)
//
#include <hip/hip_runtime.h>

typedef __bf16 bf16;
typedef __bf16 bf16x4 __attribute__((ext_vector_type(4)));
typedef __bf16 bf16x8 __attribute__((ext_vector_type(8)));
typedef float f32x4 __attribute__((ext_vector_type(4)));

constexpr int BATCH = 2;
constexpr int SEQ   = 2048;
constexpr int DMODEL= 1024;
constexpr int NH    = 16;
constexpr int HD    = 64;
constexpr int M_ROWS= BATCH * SEQ;      // 4096
constexpr int N_QKV = 3 * DMODEL;       // 3072

// async global->LDS, 16B per lane; LDS dest is wave-uniform base + lane*16
__device__ __forceinline__ void gl_lds16(const bf16* g, bf16* l) {
  __builtin_amdgcn_global_load_lds(
      (const __attribute__((address_space(1))) unsigned int*)g,
      (__attribute__((address_space(3))) unsigned int*)l, 16, 0, 0);
}

// ---------------------------------------------------------------------------
// Transpose + cast fp32 [R][C] -> bf16 [C][R]
// ---------------------------------------------------------------------------
__global__ __launch_bounds__(256) void transpose_cast_kernel(
    const float* __restrict__ src, bf16* __restrict__ dst, int R, int C) {
  __shared__ float tile[32][33];
  const int c0 = blockIdx.x * 32, r0 = blockIdx.y * 32;
  const int tx = threadIdx.x, ty = threadIdx.y;  // blockDim = (32, 8)
#pragma unroll
  for (int i = 0; i < 4; i++)
    tile[ty + 8 * i][tx] = src[(size_t)(r0 + ty + 8 * i) * C + c0 + tx];
  __syncthreads();
#pragma unroll
  for (int i = 0; i < 4; i++)
    dst[(size_t)(c0 + ty + 8 * i) * R + r0 + tx] = (bf16)tile[tx][ty + 8 * i];
}

// ---------------------------------------------------------------------------
// Cast fp32 -> bf16 elementwise (8 elems/thread)
// ---------------------------------------------------------------------------
__global__ __launch_bounds__(256) void cast_f32_bf16(
    const float* __restrict__ src, bf16* __restrict__ dst) {
  const int i = (blockIdx.x * 256 + threadIdx.x) * 8;
  float4 f0 = *(const float4*)&src[i];
  float4 f1 = *(const float4*)&src[i + 4];
  bf16x8 v;
  v[0] = (bf16)f0.x; v[1] = (bf16)f0.y; v[2] = (bf16)f0.z; v[3] = (bf16)f0.w;
  v[4] = (bf16)f1.x; v[5] = (bf16)f1.y; v[6] = (bf16)f1.z; v[7] = (bf16)f1.w;
  *(bf16x8*)&dst[i] = v;
}

// ---------------------------------------------------------------------------
// GEMM core macro-structure (m97): 128x128 tile, BK=32, 256 threads,
// unpadded LDS + global_load_lds width 16.
// ---------------------------------------------------------------------------
#define GEMM_BODY(A, BT, K)                                                    \
  __shared__ bf16 As[128 * 32];                                                \
  __shared__ bf16 Bs[128 * 32];                                                \
  const int t = threadIdx.x;                                                   \
  const int m0 = blockIdx.y * 128;                                             \
  const int n0 = blockIdx.x * 128;                                             \
  const int w = t >> 6, lane = t & 63, g = lane >> 4, li = lane & 15;          \
  const int r0w = (w & 1) * 64, c0w = (w >> 1) * 64;                           \
  f32x4 acc[4][4] = {};                                                        \
  for (int k0 = 0; k0 < (K); k0 += 32) {                                       \
    __syncthreads();                                                           \
    _Pragma("unroll") for (int c = 0; c < 2; c++) {                            \
      const int idx = (w * 2 + c) * 64 + lane;                                 \
      const int row = idx >> 2, col = (idx & 3) * 8;                           \
      gl_lds16(&(A)[(size_t)(m0 + row) * (K) + k0 + col],                      \
               &As[(w * 2 + c) * 512]);                                        \
      gl_lds16(&(BT)[(size_t)(n0 + row) * (K) + k0 + col],                     \
               &Bs[(w * 2 + c) * 512]);                                        \
    }                                                                          \
    __syncthreads();                                                           \
    bf16x8 a[4], b[4];                                                         \
    _Pragma("unroll") for (int mt = 0; mt < 4; mt++)                           \
        a[mt] = *(const bf16x8*)&As[(r0w + mt * 16 + li) * 32 + g * 8];        \
    _Pragma("unroll") for (int nt = 0; nt < 4; nt++)                           \
        b[nt] = *(const bf16x8*)&Bs[(c0w + nt * 16 + li) * 32 + g * 8];        \
    _Pragma("unroll") for (int mt = 0; mt < 4; mt++)                           \
        _Pragma("unroll") for (int nt = 0; nt < 4; nt++)                       \
            acc[mt][nt] = __builtin_amdgcn_mfma_f32_16x16x32_bf16(             \
                a[mt], b[nt], acc[mt][nt], 0, 0, 0);                           \
  }

// ---------------------------------------------------------------------------
// Out-projection GEMM: C fp32 [M][N] = A[M][K] * BT[N][K]^T
// ---------------------------------------------------------------------------
__global__ __launch_bounds__(256) void gemm_out(
    const bf16* __restrict__ A, const bf16* __restrict__ BT,
    float* __restrict__ C, int M, int N, int K) {
  GEMM_BODY(A, BT, K)
#pragma unroll
  for (int mt = 0; mt < 4; mt++)
#pragma unroll
    for (int nt = 0; nt < 4; nt++)
#pragma unroll
      for (int r = 0; r < 4; r++) {
        const int m = m0 + r0w + mt * 16 + g * 4 + r;
        const int n = n0 + c0w + nt * 16 + li;
        C[(size_t)m * N + n] = acc[mt][nt][r];
      }
}

// ---------------------------------------------------------------------------
// QKV GEMM with fused RoPE + scatter.  Q additionally pre-scaled by
// 1/sqrt(hd)*log2(e) so flash_attn can exp2 the raw MFMA output.
// ---------------------------------------------------------------------------
__global__ __launch_bounds__(256) void gemm_qkv_rope(
    const bf16* __restrict__ A, const bf16* __restrict__ BT,
    bf16* __restrict__ Qb, bf16* __restrict__ Kb, bf16* __restrict__ Vt) {
  constexpr int K = DMODEL;
  GEMM_BODY(A, BT, K)

  const int region = n0 >> 10;               // 0=q, 1=k, 2=v
  const int b = m0 >> 11;                    // batch (block-uniform)
  const int h = ((n0 + c0w) >> 6) & 15;      // head (wave-uniform)
  const size_t bh = (size_t)(b * NH + h);

  if (region < 2) {
    bf16* dst = region == 0 ? Qb : Kb;
    const float outsc = region == 0 ? 0.125f * 1.44269504f : 1.f;
    const float L = 13.287712379549449f;  // log2(10000)
    const float if0 = exp2f(-(float)(2 * li) / 64.f * L);
    const float if1 = exp2f(-(float)(2 * (li + 16)) / 64.f * L);
#pragma unroll
    for (int mt = 0; mt < 4; mt++)
#pragma unroll
      for (int r = 0; r < 4; r++) {
        const int s = (m0 + r0w + mt * 16 + g * 4 + r) & (SEQ - 1);
        float cs[2], sn[2];
        __sincosf((float)s * if0, &sn[0], &cs[0]);
        __sincosf((float)s * if1, &sn[1], &cs[1]);
#pragma unroll
        for (int nt = 0; nt < 4; nt++) {
          const int d = nt * 16 + li;
          const int par = nt & 1;
          const float a = acc[mt][nt][r];
          const float ap = acc[mt][nt ^ 2][r];
          const float v = (nt < 2) ? a * cs[par] - ap * sn[par]
                                   : a * cs[par] + ap * sn[par];
          dst[(bh * SEQ + s) * HD + d] = (bf16)(v * outsc);
        }
      }
  } else {
    // V: transpose-scatter, pack 4 consecutive s per store
#pragma unroll
    for (int mt = 0; mt < 4; mt++)
#pragma unroll
      for (int nt = 0; nt < 4; nt++) {
        const int s = (m0 + r0w + mt * 16 + g * 4) & (SEQ - 1);
        const int d = nt * 16 + li;
        bf16x4 v;
#pragma unroll
        for (int r = 0; r < 4; r++) v[r] = (bf16)acc[mt][nt][r];
        *(bf16x4*)&Vt[(bh * HD + d) * SEQ + s] = v;
      }
  }
}

// ---------------------------------------------------------------------------
// Flash attention v5 (causal): BQ=128, BK=64, 8 waves x 16 q-rows,
// 512 threads, 2 blocks/CU -> 16 waves/CU (4/SIMD).
// Fixed-max softmax in exp2 domain (Q pre-scaled), deferred l-reduce.
// K/V double-buffered via global_load_lds + XOR chunk swizzle; P in per-wave
// swizzled chunks (16 KB total, no pad).  LDS = 48 KB.
// Complementary-pair 1-D grid: CU's two blocks total 18 iter-units.
// ---------------------------------------------------------------------------
__global__ __launch_bounds__(512, 4) void flash_attn5(
    const bf16* __restrict__ Q, const bf16* __restrict__ Kb,
    const bf16* __restrict__ Vt, bf16* __restrict__ Oout) {
  const int f = blockIdx.x;          // 0..511
  const int c = f & 255, half = f >> 8;
  const int bh = c >> 3, idx = c & 7;
  const int qt = half ? 15 - idx : idx;
  const int q0 = qt * 128;
  const int t = threadIdx.x, w = t >> 6, lane = t & 63, g = lane >> 4,
            li = lane & 15;

  // 64x64 tiles as 512 chunks of 8 bf16; chunk p holds row p>>3,
  // source col group (p&7)^(row&7)  (XOR swizzle -> conflict-free b128 reads)
  __shared__ bf16 Ks[2][4096];
  __shared__ bf16 Vs[2][4096];
  __shared__ bf16 Pl[8 * 1024];     // per-wave 16x64 P tile, chunk-swizzled

  const bf16* Qh = Q  + (size_t)bh * SEQ * HD;
  const bf16* Kh = Kb + (size_t)bh * SEQ * HD;
  const bf16* Vh = Vt + (size_t)bh * HD * SEQ;

  const int qw = q0 + w * 16;        // this wave's 16 q-rows

  bf16x8 qf[2];
#pragma unroll
  for (int ks = 0; ks < 2; ks++)
    qf[ks] = *(const bf16x8*)&Qh[(size_t)(qw + li) * HD + ks * 32 + g * 8];

  f32x4 o[4] = {};
  float l_[4] = {};

  // staging: lane supplies chunk p = w*64+lane (1 gl_lds16 per wave per tile)
  const int p = w * 64 + lane;
  const int sr = p >> 3, sc = ((p & 7) ^ (sr & 7)) * 8;
  const int ldsoff = w * 512;        // elements

  const int jend = q0 + 128;
  gl_lds16(&Kh[(size_t)sr * HD + sc], &Ks[0][ldsoff]);
  gl_lds16(&Vh[(size_t)sr * SEQ + sc], &Vs[0][ldsoff]);
  __syncthreads();

  for (int j0 = 0; j0 < jend; j0 += 64) {
    const int cur = (j0 >> 6) & 1, nxt = cur ^ 1;
    if (j0 + 64 < jend) {
      const int jn = j0 + 64;
      gl_lds16(&Kh[(size_t)(jn + sr) * HD + sc], &Ks[nxt][ldsoff]);
      gl_lds16(&Vh[(size_t)sr * SEQ + jn + sc], &Vs[nxt][ldsoff]);
    }

    if (j0 <= qw + 15) {  // wave-uniform: skip fully-masked tiles
      const bool masked = (j0 + 63 > qw);
      const int ntlim = masked ? ((qw + 15 - j0) >> 4) + 1 : 4;

      // ---- S = Q K^T (exp2 domain: Q pre-scaled upstream) ----
      f32x4 sacc[4] = {};
#pragma unroll
      for (int ks = 0; ks < 2; ks++)
#pragma unroll
        for (int nt = 0; nt < 4; nt++) {
          if (nt >= ntlim) continue;  // wave-uniform strip skip
          const int rK = nt * 16 + li;
          const int pK = rK * 8 + ((ks * 4 + g) ^ (li & 7));
          bf16x8 kf = *(const bf16x8*)&Ks[cur][pK * 8];
          sacc[nt] = __builtin_amdgcn_mfma_f32_16x16x32_bf16(qf[ks], kf,
                                                             sacc[nt], 0, 0, 0);
        }

      // ---- P = 2^S (+mask on diagonal strips), per-lane l partial ----
#pragma unroll
      for (int nt = 0; nt < 4; nt++)
#pragma unroll
        for (int r = 0; r < 4; r++) {
          const int row = g * 4 + r, col = nt * 16 + li;
          const int ch = row * 8 + ((col >> 3) ^ (row & 7));
          bf16 pv;
          if (nt < ntlim) {
            float v = sacc[nt][r];
            if (masked) v = (j0 + col <= qw + row) ? v : -1e30f;
            const float pe = exp2f(v);
            l_[r] += pe;
            pv = (bf16)pe;
          } else {
            pv = (bf16)0.f;
          }
          Pl[w * 1024 + ch * 8 + (col & 7)] = pv;
        }

      // ---- O += P V (per-wave P region: wave-internal dependency only) ----
      bf16x8 pf[2];
#pragma unroll
      for (int ks = 0; ks < 2; ks++) {
        const int pP = li * 8 + ((ks * 4 + g) ^ (li & 7));
        pf[ks] = *(const bf16x8*)&Pl[w * 1024 + pP * 8];
      }
#pragma unroll
      for (int ks = 0; ks < 2; ks++)
#pragma unroll
        for (int dt = 0; dt < 4; dt++) {
          const int rV = dt * 16 + li;
          const int pV = rV * 8 + ((ks * 4 + g) ^ (li & 7));
          bf16x8 vf = *(const bf16x8*)&Vs[cur][pV * 8];
          o[dt] = __builtin_amdgcn_mfma_f32_16x16x32_bf16(pf[ks], vf, o[dt],
                                                          0, 0, 0);
        }
    }
    __syncthreads();  // drains next-tile DMA; fences cur-buf reuse
  }

  // ---- deferred l reduction across the 16 li lanes ----
#pragma unroll
  for (int off = 1; off < 16; off <<= 1)
#pragma unroll
    for (int r = 0; r < 4; r++) l_[r] += __shfl_xor(l_[r], off, 64);

  // ---- epilogue ----
  const int b = bh >> 4, h = bh & 15;
#pragma unroll
  for (int dt = 0; dt < 4; dt++)
#pragma unroll
    for (int r = 0; r < 4; r++) {
      const int s = qw + g * 4 + r;
      const int d = dt * 16 + li;
      Oout[((size_t)(b * SEQ + s)) * DMODEL + h * 64 + d] =
          (bf16)(o[dt][r] / l_[r]);
    }
}

// ---------------------------------------------------------------------------
// Launch
// ---------------------------------------------------------------------------
extern "C" void kernel_launch(void* const* d_in, const int* in_sizes, int n_in,
                              void* d_out, int out_size, void* d_ws,
                              size_t ws_size, hipStream_t stream) {
  const float* x     = (const float*)d_in[0];
  // d_in[1] = causal mask (int32) — causality implemented directly
  const float* w_qkv = (const float*)d_in[2];
  const float* w_out = (const float*)d_in[3];
  float* out = (float*)d_out;

  char* ws = (char*)d_ws;
  bf16* WqkvT = (bf16*)(ws);                        //  6,291,456 B
  bf16* WoutT = (bf16*)(ws + 6291456);              //  2,097,152 B
  bf16* xb    = (bf16*)(ws + 8388608);              //  8,388,608 B
  bf16* Qb    = (bf16*)(ws + 16777216);             //  8,388,608 B
  bf16* Kbuf  = (bf16*)(ws + 25165824);             //  8,388,608 B
  bf16* Vt    = (bf16*)(ws + 33554432);             //  8,388,608 B
  bf16* attn  = (bf16*)(ws + 41943040);             //  8,388,608 B (end ~48MB)

  cast_f32_bf16<<<M_ROWS * DMODEL / 2048, 256, 0, stream>>>(x, xb);
  transpose_cast_kernel<<<dim3(N_QKV / 32, DMODEL / 32), dim3(32, 8), 0,
                          stream>>>(w_qkv, WqkvT, DMODEL, N_QKV);
  transpose_cast_kernel<<<dim3(DMODEL / 32, DMODEL / 32), dim3(32, 8), 0,
                          stream>>>(w_out, WoutT, DMODEL, DMODEL);
  gemm_qkv_rope<<<dim3(N_QKV / 128, M_ROWS / 128), 256, 0, stream>>>(
      xb, WqkvT, Qb, Kbuf, Vt);
  flash_attn5<<<dim3(512), 512, 0, stream>>>(Qb, Kbuf, Vt, attn);
  gemm_out<<<dim3(DMODEL / 128, M_ROWS / 128), 256, 0, stream>>>(
      attn, WoutT, out, M_ROWS, DMODEL, DMODEL);
}

// Round 7
// 220.079 us; speedup vs baseline: 1.0451x; 1.0451x over previous
//
#include <hip/hip_runtime.h>

typedef __bf16 bf16;
typedef __bf16 bf16x4 __attribute__((ext_vector_type(4)));
typedef __bf16 bf16x8 __attribute__((ext_vector_type(8)));
typedef short s16x4 __attribute__((ext_vector_type(4)));
typedef float f32x4 __attribute__((ext_vector_type(4)));

constexpr int BATCH = 2;
constexpr int SEQ   = 2048;
constexpr int DMODEL= 1024;
constexpr int NH    = 16;
constexpr int HD    = 64;
constexpr int M_ROWS= BATCH * SEQ;      // 4096
constexpr int N_QKV = 3 * DMODEL;       // 3072

// async global->LDS, 16B per lane; LDS dest is wave-uniform base + lane*16
__device__ __forceinline__ void gl_lds16(const bf16* g, bf16* l) {
  __builtin_amdgcn_global_load_lds(
      (const __attribute__((address_space(1))) unsigned int*)g,
      (__attribute__((address_space(3))) unsigned int*)l, 16, 0, 0);
}

// K=16 bf16 MFMA: v_mfma_f32_16x16x16_bf16 (gfx90a-lineage builtin, takes
// short4).  Host pass has no amdgcn builtins -> trivial fallback there.
__device__ __forceinline__ f32x4 mfma_16x16x16_bf16(bf16x4 a, bf16x4 b,
                                                    f32x4 c) {
#if defined(__HIP_DEVICE_COMPILE__)
  union { bf16x4 h; s16x4 s; } ua{a}, ub{b};
  return __builtin_amdgcn_mfma_f32_16x16x16bf16_1k(ua.s, ub.s, c, 0, 0, 0);
#else
  return c;  // never executed; host pass only needs this to parse
#endif
}

// ---------------------------------------------------------------------------
// Transpose + cast fp32 [R][C] -> bf16 [C][R]
// ---------------------------------------------------------------------------
__global__ __launch_bounds__(256) void transpose_cast_kernel(
    const float* __restrict__ src, bf16* __restrict__ dst, int R, int C) {
  __shared__ float tile[32][33];
  const int c0 = blockIdx.x * 32, r0 = blockIdx.y * 32;
  const int tx = threadIdx.x, ty = threadIdx.y;  // blockDim = (32, 8)
#pragma unroll
  for (int i = 0; i < 4; i++)
    tile[ty + 8 * i][tx] = src[(size_t)(r0 + ty + 8 * i) * C + c0 + tx];
  __syncthreads();
#pragma unroll
  for (int i = 0; i < 4; i++)
    dst[(size_t)(c0 + ty + 8 * i) * R + r0 + tx] = (bf16)tile[tx][ty + 8 * i];
}

// ---------------------------------------------------------------------------
// Cast fp32 -> bf16 elementwise (8 elems/thread)
// ---------------------------------------------------------------------------
__global__ __launch_bounds__(256) void cast_f32_bf16(
    const float* __restrict__ src, bf16* __restrict__ dst) {
  const int i = (blockIdx.x * 256 + threadIdx.x) * 8;
  float4 f0 = *(const float4*)&src[i];
  float4 f1 = *(const float4*)&src[i + 4];
  bf16x8 v;
  v[0] = (bf16)f0.x; v[1] = (bf16)f0.y; v[2] = (bf16)f0.z; v[3] = (bf16)f0.w;
  v[4] = (bf16)f1.x; v[5] = (bf16)f1.y; v[6] = (bf16)f1.z; v[7] = (bf16)f1.w;
  *(bf16x8*)&dst[i] = v;
}

// ---------------------------------------------------------------------------
// GEMM core macro-structure (m97): 128x128 tile, BK=32, 256 threads,
// unpadded LDS + global_load_lds width 16.
// ---------------------------------------------------------------------------
#define GEMM_BODY(A, BT, K)                                                    \
  __shared__ bf16 As[128 * 32];                                                \
  __shared__ bf16 Bs[128 * 32];                                                \
  const int t = threadIdx.x;                                                   \
  const int m0 = blockIdx.y * 128;                                             \
  const int n0 = blockIdx.x * 128;                                             \
  const int w = t >> 6, lane = t & 63, g = lane >> 4, li = lane & 15;          \
  const int r0w = (w & 1) * 64, c0w = (w >> 1) * 64;                           \
  f32x4 acc[4][4] = {};                                                        \
  for (int k0 = 0; k0 < (K); k0 += 32) {                                       \
    __syncthreads();                                                           \
    _Pragma("unroll") for (int c = 0; c < 2; c++) {                            \
      const int idx = (w * 2 + c) * 64 + lane;                                 \
      const int row = idx >> 2, col = (idx & 3) * 8;                           \
      gl_lds16(&(A)[(size_t)(m0 + row) * (K) + k0 + col],                      \
               &As[(w * 2 + c) * 512]);                                        \
      gl_lds16(&(BT)[(size_t)(n0 + row) * (K) + k0 + col],                     \
               &Bs[(w * 2 + c) * 512]);                                        \
    }                                                                          \
    __syncthreads();                                                           \
    bf16x8 a[4], b[4];                                                         \
    _Pragma("unroll") for (int mt = 0; mt < 4; mt++)                           \
        a[mt] = *(const bf16x8*)&As[(r0w + mt * 16 + li) * 32 + g * 8];        \
    _Pragma("unroll") for (int nt = 0; nt < 4; nt++)                           \
        b[nt] = *(const bf16x8*)&Bs[(c0w + nt * 16 + li) * 32 + g * 8];        \
    _Pragma("unroll") for (int mt = 0; mt < 4; mt++)                           \
        _Pragma("unroll") for (int nt = 0; nt < 4; nt++)                       \
            acc[mt][nt] = __builtin_amdgcn_mfma_f32_16x16x32_bf16(             \
                a[mt], b[nt], acc[mt][nt], 0, 0, 0);                           \
  }

// ---------------------------------------------------------------------------
// Out-projection GEMM: C fp32 [M][N] = A[M][K] * BT[N][K]^T
// ---------------------------------------------------------------------------
__global__ __launch_bounds__(256) void gemm_out(
    const bf16* __restrict__ A, const bf16* __restrict__ BT,
    float* __restrict__ C, int M, int N, int K) {
  GEMM_BODY(A, BT, K)
#pragma unroll
  for (int mt = 0; mt < 4; mt++)
#pragma unroll
    for (int nt = 0; nt < 4; nt++)
#pragma unroll
      for (int r = 0; r < 4; r++) {
        const int m = m0 + r0w + mt * 16 + g * 4 + r;
        const int n = n0 + c0w + nt * 16 + li;
        C[(size_t)m * N + n] = acc[mt][nt][r];
      }
}

// ---------------------------------------------------------------------------
// QKV GEMM with fused RoPE + scatter.  Q additionally pre-scaled by
// 1/sqrt(hd)*log2(e) so flash_attn can exp2 the raw MFMA output.
// ---------------------------------------------------------------------------
__global__ __launch_bounds__(256) void gemm_qkv_rope(
    const bf16* __restrict__ A, const bf16* __restrict__ BT,
    bf16* __restrict__ Qb, bf16* __restrict__ Kb, bf16* __restrict__ Vt) {
  constexpr int K = DMODEL;
  GEMM_BODY(A, BT, K)

  const int region = n0 >> 10;               // 0=q, 1=k, 2=v
  const int b = m0 >> 11;                    // batch (block-uniform)
  const int h = ((n0 + c0w) >> 6) & 15;      // head (wave-uniform)
  const size_t bh = (size_t)(b * NH + h);

  if (region < 2) {
    bf16* dst = region == 0 ? Qb : Kb;
    const float outsc = region == 0 ? 0.125f * 1.44269504f : 1.f;
    const float L = 13.287712379549449f;  // log2(10000)
    const float if0 = exp2f(-(float)(2 * li) / 64.f * L);
    const float if1 = exp2f(-(float)(2 * (li + 16)) / 64.f * L);
#pragma unroll
    for (int mt = 0; mt < 4; mt++)
#pragma unroll
      for (int r = 0; r < 4; r++) {
        const int s = (m0 + r0w + mt * 16 + g * 4 + r) & (SEQ - 1);
        float cs[2], sn[2];
        __sincosf((float)s * if0, &sn[0], &cs[0]);
        __sincosf((float)s * if1, &sn[1], &cs[1]);
#pragma unroll
        for (int nt = 0; nt < 4; nt++) {
          const int d = nt * 16 + li;
          const int par = nt & 1;
          const float a = acc[mt][nt][r];
          const float ap = acc[mt][nt ^ 2][r];
          const float v = (nt < 2) ? a * cs[par] - ap * sn[par]
                                   : a * cs[par] + ap * sn[par];
          dst[(bh * SEQ + s) * HD + d] = (bf16)(v * outsc);
        }
      }
  } else {
    // V: transpose-scatter, pack 4 consecutive s per store
#pragma unroll
    for (int mt = 0; mt < 4; mt++)
#pragma unroll
      for (int nt = 0; nt < 4; nt++) {
        const int s = (m0 + r0w + mt * 16 + g * 4) & (SEQ - 1);
        const int d = nt * 16 + li;
        bf16x4 v;
#pragma unroll
        for (int r = 0; r < 4; r++) v[r] = (bf16)acc[mt][nt][r];
        *(bf16x4*)&Vt[(bh * HD + d) * SEQ + s] = v;
      }
  }
}

// ---------------------------------------------------------------------------
// Flash attention v6 (causal): BQ=128, BK=64, 8 waves x 16 q-rows, 512 thr.
// S^T trick: S^T = K·Q^T via 16x16x32 (k on (g,r), q on li); P^T in C-layout
// feeds the PV MFMA (16x16x16, B-operand k=g*4+j) DIRECTLY from registers —
// no P LDS round-trip.  O^T = V^T·P^T accumulated in C-layout (dv on (g,r),
// q on li).  Fixed-max exp2 softmax (Q pre-scaled), scalar per-lane l.
// K/V double-buffered via global_load_lds + XOR chunk swizzle.  LDS = 32 KB.
// ---------------------------------------------------------------------------
__global__ __launch_bounds__(512, 4) void flash_attn6(
    const bf16* __restrict__ Q, const bf16* __restrict__ Kb,
    const bf16* __restrict__ Vt, bf16* __restrict__ Oout) {
  const int f = blockIdx.x;          // 0..511
  const int c = f & 255, half = f >> 8;
  const int bh = c >> 3, idx = c & 7;
  const int qt = half ? 15 - idx : idx;
  const int q0 = qt * 128;
  const int t = threadIdx.x, w = t >> 6, lane = t & 63, g = lane >> 4,
            li = lane & 15;

  // 64x64 tiles as 512 chunks of 8 bf16; chunk p holds row p>>3,
  // source col group (p&7)^(row&7)  (XOR swizzle -> conflict-free reads)
  __shared__ bf16 Ks[2][4096];
  __shared__ bf16 Vs[2][4096];

  const bf16* Qh = Q  + (size_t)bh * SEQ * HD;
  const bf16* Kh = Kb + (size_t)bh * SEQ * HD;
  const bf16* Vh = Vt + (size_t)bh * HD * SEQ;

  const int qw = q0 + w * 16;        // this wave's 16 q-rows (q = qw + li)

  bf16x8 qf[2];
#pragma unroll
  for (int ks = 0; ks < 2; ks++)
    qf[ks] = *(const bf16x8*)&Qh[(size_t)(qw + li) * HD + ks * 32 + g * 8];

  f32x4 o[4] = {};   // O^T[dv = dt*16 + g*4 + r][q = li]
  float l_ = 0.f;    // per-lane partial: q = li, k in this lane's g-group

  // staging: lane supplies chunk p = w*64+lane (1 gl_lds16 per wave per tile)
  const int p = w * 64 + lane;
  const int sr = p >> 3, sc = ((p & 7) ^ (sr & 7)) * 8;
  const int ldsoff = w * 512;        // elements

  const int jend = q0 + 128;
  gl_lds16(&Kh[(size_t)sr * HD + sc], &Ks[0][ldsoff]);
  gl_lds16(&Vh[(size_t)sr * SEQ + sc], &Vs[0][ldsoff]);
  __syncthreads();

  for (int j0 = 0; j0 < jend; j0 += 64) {
    const int cur = (j0 >> 6) & 1, nxt = cur ^ 1;
    if (j0 + 64 < jend) {
      const int jn = j0 + 64;
      gl_lds16(&Kh[(size_t)(jn + sr) * HD + sc], &Ks[nxt][ldsoff]);
      gl_lds16(&Vh[(size_t)sr * SEQ + jn + sc], &Vs[nxt][ldsoff]);
    }

    if (j0 <= qw + 15) {  // wave-uniform: skip fully-masked tiles
      const bool masked = (j0 + 63 > qw);
      const int ntlim = min(4, ((qw + 15 - j0) >> 4) + 1);

      // ---- S^T = K Q^T (exp2 domain: Q pre-scaled upstream) ----
      f32x4 sacc[4] = {};
#pragma unroll
      for (int ks = 0; ks < 2; ks++)
#pragma unroll
        for (int nt = 0; nt < 4; nt++) {
          if (nt >= ntlim) continue;  // wave-uniform strip skip
          const int rK = nt * 16 + li;
          const int pK = rK * 8 + ((ks * 4 + g) ^ (li & 7));
          bf16x8 kf = *(const bf16x8*)&Ks[cur][pK * 8];
          sacc[nt] = __builtin_amdgcn_mfma_f32_16x16x32_bf16(kf, qf[ks],
                                                             sacc[nt], 0, 0, 0);
        }

      // ---- P^T = 2^(S^T) (+mask on diagonal strips) in registers ----
      bf16x4 pf[4];
#pragma unroll
      for (int nt = 0; nt < 4; nt++) {
        if (nt >= ntlim) continue;
#pragma unroll
        for (int r = 0; r < 4; r++) {
          float v = sacc[nt][r];
          if (masked) {
            const int kk = j0 + nt * 16 + g * 4 + r;  // abs key index
            v = (kk <= qw + li) ? v : -1e30f;         // q = qw + li
          }
          const float pe = exp2f(v);
          l_ += pe;
          pf[nt][r] = (bf16)pe;
        }
      }

      // ---- O^T += V^T P^T  (A = V^T frag from LDS, B = pf registers) ----
#pragma unroll
      for (int nt = 0; nt < 4; nt++) {
        if (nt >= ntlim) continue;
#pragma unroll
        for (int dt = 0; dt < 4; dt++) {
          const int rV = dt * 16 + li;                     // dv row in Vs
          const int cg = nt * 2 + (g >> 1);                // col group of 8
          const int pV = rV * 8 + (cg ^ (rV & 7));
          bf16x4 vfrag = *(const bf16x4*)&Vs[cur][pV * 8 + (g & 1) * 4];
          o[dt] = mfma_16x16x16_bf16(vfrag, pf[nt], o[dt]);
        }
      }
    }
    __syncthreads();  // drains next-tile DMA; fences cur-buf reuse
  }

  // ---- l reduction across the 4 g-groups (q = li fixed per lane) ----
  l_ += __shfl_xor(l_, 16, 64);
  l_ += __shfl_xor(l_, 32, 64);
  const float inv_l = 1.f / l_;

  // ---- epilogue: O^T -> attn[b*S+s][h*64+dv], 4x bf16x4 stores ----
  const int b = bh >> 4, h = bh & 15;
  const int s = qw + li;
#pragma unroll
  for (int dt = 0; dt < 4; dt++) {
    bf16x4 ov;
#pragma unroll
    for (int r = 0; r < 4; r++) ov[r] = (bf16)(o[dt][r] * inv_l);
    *(bf16x4*)&Oout[((size_t)(b * SEQ + s)) * DMODEL + h * 64 + dt * 16 +
                    g * 4] = ov;
  }
}

// ---------------------------------------------------------------------------
// Launch
// ---------------------------------------------------------------------------
extern "C" void kernel_launch(void* const* d_in, const int* in_sizes, int n_in,
                              void* d_out, int out_size, void* d_ws,
                              size_t ws_size, hipStream_t stream) {
  const float* x     = (const float*)d_in[0];
  // d_in[1] = causal mask (int32) — causality implemented directly
  const float* w_qkv = (const float*)d_in[2];
  const float* w_out = (const float*)d_in[3];
  float* out = (float*)d_out;

  char* ws = (char*)d_ws;
  bf16* WqkvT = (bf16*)(ws);                        //  6,291,456 B
  bf16* WoutT = (bf16*)(ws + 6291456);              //  2,097,152 B
  bf16* xb    = (bf16*)(ws + 8388608);              //  8,388,608 B
  bf16* Qb    = (bf16*)(ws + 16777216);             //  8,388,608 B
  bf16* Kbuf  = (bf16*)(ws + 25165824);             //  8,388,608 B
  bf16* Vt    = (bf16*)(ws + 33554432);             //  8,388,608 B
  bf16* attn  = (bf16*)(ws + 41943040);             //  8,388,608 B (end ~48MB)

  cast_f32_bf16<<<M_ROWS * DMODEL / 2048, 256, 0, stream>>>(x, xb);
  transpose_cast_kernel<<<dim3(N_QKV / 32, DMODEL / 32), dim3(32, 8), 0,
                          stream>>>(w_qkv, WqkvT, DMODEL, N_QKV);
  transpose_cast_kernel<<<dim3(DMODEL / 32, DMODEL / 32), dim3(32, 8), 0,
                          stream>>>(w_out, WoutT, DMODEL, DMODEL);
  gemm_qkv_rope<<<dim3(N_QKV / 128, M_ROWS / 128), 256, 0, stream>>>(
      xb, WqkvT, Qb, Kbuf, Vt);
  flash_attn6<<<dim3(512), 512, 0, stream>>>(Qb, Kbuf, Vt, attn);
  gemm_out<<<dim3(DMODEL / 128, M_ROWS / 128), 256, 0, stream>>>(
      attn, WoutT, out, M_ROWS, DMODEL, DMODEL);
}

// Round 8
// 217.400 us; speedup vs baseline: 1.0580x; 1.0123x over previous
//
#include <hip/hip_runtime.h>

typedef __bf16 bf16;
typedef __bf16 bf16x4 __attribute__((ext_vector_type(4)));
typedef __bf16 bf16x8 __attribute__((ext_vector_type(8)));
typedef short s16x4 __attribute__((ext_vector_type(4)));
typedef float f32x4 __attribute__((ext_vector_type(4)));

constexpr int BATCH = 2;
constexpr int SEQ   = 2048;
constexpr int DMODEL= 1024;
constexpr int NH    = 16;
constexpr int HD    = 64;
constexpr int M_ROWS= BATCH * SEQ;      // 4096
constexpr int N_QKV = 3 * DMODEL;       // 3072

// async global->LDS, 16B per lane; LDS dest is wave-uniform base + lane*16
__device__ __forceinline__ void gl_lds16(const bf16* g, bf16* l) {
  __builtin_amdgcn_global_load_lds(
      (const __attribute__((address_space(1))) unsigned int*)g,
      (__attribute__((address_space(3))) unsigned int*)l, 16, 0, 0);
}

// K=16 bf16 MFMA: v_mfma_f32_16x16x16_bf16 (gfx90a-lineage builtin, takes
// short4).  Host pass has no amdgcn builtins -> trivial fallback there.
__device__ __forceinline__ f32x4 mfma_16x16x16_bf16(bf16x4 a, bf16x4 b,
                                                    f32x4 c) {
#if defined(__HIP_DEVICE_COMPILE__)
  union { bf16x4 h; s16x4 s; } ua{a}, ub{b};
  return __builtin_amdgcn_mfma_f32_16x16x16bf16_1k(ua.s, ub.s, c, 0, 0, 0);
#else
  return c;  // never executed; host pass only needs this to parse
#endif
}

// ---------------------------------------------------------------------------
// Transpose + cast fp32 [R][C] -> bf16 [C][R]
// ---------------------------------------------------------------------------
__global__ __launch_bounds__(256) void transpose_cast_kernel(
    const float* __restrict__ src, bf16* __restrict__ dst, int R, int C) {
  __shared__ float tile[32][33];
  const int c0 = blockIdx.x * 32, r0 = blockIdx.y * 32;
  const int tx = threadIdx.x, ty = threadIdx.y;  // blockDim = (32, 8)
#pragma unroll
  for (int i = 0; i < 4; i++)
    tile[ty + 8 * i][tx] = src[(size_t)(r0 + ty + 8 * i) * C + c0 + tx];
  __syncthreads();
#pragma unroll
  for (int i = 0; i < 4; i++)
    dst[(size_t)(c0 + ty + 8 * i) * R + r0 + tx] = (bf16)tile[tx][ty + 8 * i];
}

// ---------------------------------------------------------------------------
// Cast fp32 -> bf16 elementwise (8 elems/thread)
// ---------------------------------------------------------------------------
__global__ __launch_bounds__(256) void cast_f32_bf16(
    const float* __restrict__ src, bf16* __restrict__ dst) {
  const int i = (blockIdx.x * 256 + threadIdx.x) * 8;
  float4 f0 = *(const float4*)&src[i];
  float4 f1 = *(const float4*)&src[i + 4];
  bf16x8 v;
  v[0] = (bf16)f0.x; v[1] = (bf16)f0.y; v[2] = (bf16)f0.z; v[3] = (bf16)f0.w;
  v[4] = (bf16)f1.x; v[5] = (bf16)f1.y; v[6] = (bf16)f1.z; v[7] = (bf16)f1.w;
  *(bf16x8*)&dst[i] = v;
}

// ---------------------------------------------------------------------------
// GEMM core macro-structure (m97): 128x128 tile, BK=32, 256 threads,
// unpadded LDS + global_load_lds width 16.
// ---------------------------------------------------------------------------
#define GEMM_BODY(A, BT, K)                                                    \
  __shared__ bf16 As[128 * 32];                                                \
  __shared__ bf16 Bs[128 * 32];                                                \
  const int t = threadIdx.x;                                                   \
  const int m0 = blockIdx.y * 128;                                             \
  const int n0 = blockIdx.x * 128;                                             \
  const int w = t >> 6, lane = t & 63, g = lane >> 4, li = lane & 15;          \
  const int r0w = (w & 1) * 64, c0w = (w >> 1) * 64;                           \
  f32x4 acc[4][4] = {};                                                        \
  for (int k0 = 0; k0 < (K); k0 += 32) {                                       \
    __syncthreads();                                                           \
    _Pragma("unroll") for (int c = 0; c < 2; c++) {                            \
      const int idx = (w * 2 + c) * 64 + lane;                                 \
      const int row = idx >> 2, col = (idx & 3) * 8;                           \
      gl_lds16(&(A)[(size_t)(m0 + row) * (K) + k0 + col],                      \
               &As[(w * 2 + c) * 512]);                                        \
      gl_lds16(&(BT)[(size_t)(n0 + row) * (K) + k0 + col],                     \
               &Bs[(w * 2 + c) * 512]);                                        \
    }                                                                          \
    __syncthreads();                                                           \
    bf16x8 a[4], b[4];                                                         \
    _Pragma("unroll") for (int mt = 0; mt < 4; mt++)                           \
        a[mt] = *(const bf16x8*)&As[(r0w + mt * 16 + li) * 32 + g * 8];        \
    _Pragma("unroll") for (int nt = 0; nt < 4; nt++)                           \
        b[nt] = *(const bf16x8*)&Bs[(c0w + nt * 16 + li) * 32 + g * 8];        \
    _Pragma("unroll") for (int mt = 0; mt < 4; mt++)                           \
        _Pragma("unroll") for (int nt = 0; nt < 4; nt++)                       \
            acc[mt][nt] = __builtin_amdgcn_mfma_f32_16x16x32_bf16(             \
                a[mt], b[nt], acc[mt][nt], 0, 0, 0);                           \
  }

// ---------------------------------------------------------------------------
// Out-projection GEMM: C fp32 [M][N] = A[M][K] * BT[N][K]^T
// ---------------------------------------------------------------------------
__global__ __launch_bounds__(256) void gemm_out(
    const bf16* __restrict__ A, const bf16* __restrict__ BT,
    float* __restrict__ C, int M, int N, int K) {
  GEMM_BODY(A, BT, K)
#pragma unroll
  for (int mt = 0; mt < 4; mt++)
#pragma unroll
    for (int nt = 0; nt < 4; nt++)
#pragma unroll
      for (int r = 0; r < 4; r++) {
        const int m = m0 + r0w + mt * 16 + g * 4 + r;
        const int n = n0 + c0w + nt * 16 + li;
        C[(size_t)m * N + n] = acc[mt][nt][r];
      }
}

// ---------------------------------------------------------------------------
// QKV GEMM with fused RoPE + scatter.  Q additionally pre-scaled by
// 1/sqrt(hd)*log2(e) so flash_attn can exp2 the raw MFMA output.
// ---------------------------------------------------------------------------
__global__ __launch_bounds__(256) void gemm_qkv_rope(
    const bf16* __restrict__ A, const bf16* __restrict__ BT,
    bf16* __restrict__ Qb, bf16* __restrict__ Kb, bf16* __restrict__ Vt) {
  constexpr int K = DMODEL;
  GEMM_BODY(A, BT, K)

  const int region = n0 >> 10;               // 0=q, 1=k, 2=v
  const int b = m0 >> 11;                    // batch (block-uniform)
  const int h = ((n0 + c0w) >> 6) & 15;      // head (wave-uniform)
  const size_t bh = (size_t)(b * NH + h);

  if (region < 2) {
    bf16* dst = region == 0 ? Qb : Kb;
    const float outsc = region == 0 ? 0.125f * 1.44269504f : 1.f;
    const float L = 13.287712379549449f;  // log2(10000)
    const float if0 = exp2f(-(float)(2 * li) / 64.f * L);
    const float if1 = exp2f(-(float)(2 * (li + 16)) / 64.f * L);
#pragma unroll
    for (int mt = 0; mt < 4; mt++)
#pragma unroll
      for (int r = 0; r < 4; r++) {
        const int s = (m0 + r0w + mt * 16 + g * 4 + r) & (SEQ - 1);
        float cs[2], sn[2];
        __sincosf((float)s * if0, &sn[0], &cs[0]);
        __sincosf((float)s * if1, &sn[1], &cs[1]);
#pragma unroll
        for (int nt = 0; nt < 4; nt++) {
          const int d = nt * 16 + li;
          const int par = nt & 1;
          const float a = acc[mt][nt][r];
          const float ap = acc[mt][nt ^ 2][r];
          const float v = (nt < 2) ? a * cs[par] - ap * sn[par]
                                   : a * cs[par] + ap * sn[par];
          dst[(bh * SEQ + s) * HD + d] = (bf16)(v * outsc);
        }
      }
  } else {
    // V: transpose-scatter, pack 4 consecutive s per store
#pragma unroll
    for (int mt = 0; mt < 4; mt++)
#pragma unroll
      for (int nt = 0; nt < 4; nt++) {
        const int s = (m0 + r0w + mt * 16 + g * 4) & (SEQ - 1);
        const int d = nt * 16 + li;
        bf16x4 v;
#pragma unroll
        for (int r = 0; r < 4; r++) v[r] = (bf16)acc[mt][nt][r];
        *(bf16x4*)&Vt[(bh * HD + d) * SEQ + s] = v;
      }
  }
}

// ---------------------------------------------------------------------------
// Flash attention v7 (causal): BQ=128, BK=64, 8 waves x 16 q-rows, 512 thr.
// S^T trick (P stays in registers).  Ring-4 K/V LDS buffers (64 KB), DMA
// issued 2 tiles ahead, ONE barrier per 2 iterations.  l accumulated via a
// ones-row MFMA (A=1): each lane ends with l(q=li) in the accumulator — no
// cross-lane reduction at all.  Fixed-max exp2 softmax (Q pre-scaled).
// ---------------------------------------------------------------------------
__global__ __launch_bounds__(512, 4) void flash_attn7(
    const bf16* __restrict__ Q, const bf16* __restrict__ Kb,
    const bf16* __restrict__ Vt, bf16* __restrict__ Oout) {
  const int f = blockIdx.x;          // 0..511, complementary-pair swizzle
  const int c = f & 255, half = f >> 8;
  const int bh = c >> 3, idx = c & 7;
  const int qt = half ? 15 - idx : idx;
  const int q0 = qt * 128;
  const int t = threadIdx.x, w = t >> 6, lane = t & 63, g = lane >> 4,
            li = lane & 15;

  // 64x64 tiles as 512 chunks of 8 bf16; chunk p holds row p>>3,
  // source col group (p&7)^(row&7)  (XOR swizzle -> conflict-free reads)
  __shared__ bf16 Ks[4][4096];
  __shared__ bf16 Vs[4][4096];

  const bf16* Qh = Q  + (size_t)bh * SEQ * HD;
  const bf16* Kh = Kb + (size_t)bh * SEQ * HD;
  const bf16* Vh = Vt + (size_t)bh * HD * SEQ;

  const int qw = q0 + w * 16;        // this wave's 16 q-rows (q = qw + li)

  bf16x8 qf[2];
#pragma unroll
  for (int ks = 0; ks < 2; ks++)
    qf[ks] = *(const bf16x8*)&Qh[(size_t)(qw + li) * HD + ks * 32 + g * 8];

  f32x4 o[4] = {};   // O^T[dv = dt*16 + g*4 + r][q = li]
  f32x4 o4  = {};    // ones-row accumulator: every element ends = l(q=li)
  bf16x4 ones;
#pragma unroll
  for (int r = 0; r < 4; r++) ones[r] = (bf16)1.f;

  // staging: lane supplies chunk p = w*64+lane (1 gl_lds16 per wave per tile)
  const int p = w * 64 + lane;
  const int sr = p >> 3, sc = ((p & 7) ^ (sr & 7)) * 8;
  const int ldsoff = w * 512;        // elements

  const int jend = q0 + 128;         // multiple of 128

  // prologue: stage tiles j=0 -> buf0, j=64 -> buf1
  gl_lds16(&Kh[(size_t)sr * HD + sc], &Ks[0][ldsoff]);
  gl_lds16(&Vh[(size_t)sr * SEQ + sc], &Vs[0][ldsoff]);
  gl_lds16(&Kh[(size_t)(64 + sr) * HD + sc], &Ks[1][ldsoff]);
  gl_lds16(&Vh[(size_t)sr * SEQ + 64 + sc], &Vs[1][ldsoff]);
  __syncthreads();

#define FA_COMPUTE(J0, BUF)                                                    \
  if ((J0) <= qw + 15) {                                                       \
    const bool masked = ((J0) + 63 > qw);                                      \
    const int ntlim = min(4, ((qw + 15 - (J0)) >> 4) + 1);                     \
    f32x4 sacc[4] = {};                                                        \
    _Pragma("unroll") for (int ks = 0; ks < 2; ks++)                           \
        _Pragma("unroll") for (int nt = 0; nt < 4; nt++) {                     \
      if (nt >= ntlim) continue;                                               \
      const int rK = nt * 16 + li;                                             \
      const int pK = rK * 8 + ((ks * 4 + g) ^ (li & 7));                       \
      bf16x8 kf = *(const bf16x8*)&Ks[BUF][pK * 8];                            \
      sacc[nt] = __builtin_amdgcn_mfma_f32_16x16x32_bf16(kf, qf[ks],           \
                                                         sacc[nt], 0, 0, 0);   \
    }                                                                          \
    bf16x4 pf[4];                                                              \
    _Pragma("unroll") for (int nt = 0; nt < 4; nt++) {                         \
      if (nt >= ntlim) continue;                                               \
      _Pragma("unroll") for (int r = 0; r < 4; r++) {                          \
        float v = sacc[nt][r];                                                 \
        if (masked) {                                                          \
          const int kk = (J0) + nt * 16 + g * 4 + r;                           \
          v = (kk <= qw + li) ? v : -1e30f;                                    \
        }                                                                      \
        pf[nt][r] = (bf16)exp2f(v);                                            \
      }                                                                        \
    }                                                                          \
    _Pragma("unroll") for (int nt = 0; nt < 4; nt++) {                         \
      if (nt >= ntlim) continue;                                               \
      o4 = mfma_16x16x16_bf16(ones, pf[nt], o4);                               \
      _Pragma("unroll") for (int dt = 0; dt < 4; dt++) {                       \
        const int rV = dt * 16 + li;                                           \
        const int cg = nt * 2 + (g >> 1);                                      \
        const int pV = rV * 8 + (cg ^ (rV & 7));                               \
        bf16x4 vfrag = *(const bf16x4*)&Vs[BUF][pV * 8 + (g & 1) * 4];         \
        o[dt] = mfma_16x16x16_bf16(vfrag, pf[nt], o[dt]);                      \
      }                                                                        \
    }                                                                          \
  }

  for (int jA = 0; jA < jend; jA += 128) {
    const int a = (jA >> 6) & 3;
    // DMA jA+128 -> buf (a+2)&3 (that buf's last readers fenced 1 barrier ago)
    if (jA + 128 < jend) {
      const int jn = jA + 128;
      bf16* kd = &Ks[(a + 2) & 3][ldsoff];
      bf16* vd = &Vs[(a + 2) & 3][ldsoff];
      gl_lds16(&Kh[(size_t)(jn + sr) * HD + sc], kd);
      gl_lds16(&Vh[(size_t)sr * SEQ + jn + sc], vd);
    }
    FA_COMPUTE(jA, a)
    const int jB = jA + 64;
    if (jB + 128 < jend) {
      const int jn = jB + 128;
      bf16* kd = &Ks[(a + 3) & 3][ldsoff];
      bf16* vd = &Vs[(a + 3) & 3][ldsoff];
      gl_lds16(&Kh[(size_t)(jn + sr) * HD + sc], kd);
      gl_lds16(&Vh[(size_t)sr * SEQ + jn + sc], vd);
    }
    FA_COMPUTE(jB, ((a + 1) & 3))
    __syncthreads();  // drains this body's DMAs; fences buf reuse
  }
#undef FA_COMPUTE

  const float inv_l = 1.f / o4[0];   // all 4 regs equal l(q=li)

  // ---- epilogue: O^T -> attn[b*S+s][h*64+dv], 4x bf16x4 stores ----
  const int b = bh >> 4, h = bh & 15;
  const int s = qw + li;
#pragma unroll
  for (int dt = 0; dt < 4; dt++) {
    bf16x4 ov;
#pragma unroll
    for (int r = 0; r < 4; r++) ov[r] = (bf16)(o[dt][r] * inv_l);
    *(bf16x4*)&Oout[((size_t)(b * SEQ + s)) * DMODEL + h * 64 + dt * 16 +
                    g * 4] = ov;
  }
}

// ---------------------------------------------------------------------------
// Launch
// ---------------------------------------------------------------------------
extern "C" void kernel_launch(void* const* d_in, const int* in_sizes, int n_in,
                              void* d_out, int out_size, void* d_ws,
                              size_t ws_size, hipStream_t stream) {
  const float* x     = (const float*)d_in[0];
  // d_in[1] = causal mask (int32) — causality implemented directly
  const float* w_qkv = (const float*)d_in[2];
  const float* w_out = (const float*)d_in[3];
  float* out = (float*)d_out;

  char* ws = (char*)d_ws;
  bf16* WqkvT = (bf16*)(ws);                        //  6,291,456 B
  bf16* WoutT = (bf16*)(ws + 6291456);              //  2,097,152 B
  bf16* xb    = (bf16*)(ws + 8388608);              //  8,388,608 B
  bf16* Qb    = (bf16*)(ws + 16777216);             //  8,388,608 B
  bf16* Kbuf  = (bf16*)(ws + 25165824);             //  8,388,608 B
  bf16* Vt    = (bf16*)(ws + 33554432);             //  8,388,608 B
  bf16* attn  = (bf16*)(ws + 41943040);             //  8,388,608 B (end ~48MB)

  cast_f32_bf16<<<M_ROWS * DMODEL / 2048, 256, 0, stream>>>(x, xb);
  transpose_cast_kernel<<<dim3(N_QKV / 32, DMODEL / 32), dim3(32, 8), 0,
                          stream>>>(w_qkv, WqkvT, DMODEL, N_QKV);
  transpose_cast_kernel<<<dim3(DMODEL / 32, DMODEL / 32), dim3(32, 8), 0,
                          stream>>>(w_out, WoutT, DMODEL, DMODEL);
  gemm_qkv_rope<<<dim3(N_QKV / 128, M_ROWS / 128), 256, 0, stream>>>(
      xb, WqkvT, Qb, Kbuf, Vt);
  flash_attn7<<<dim3(512), 512, 0, stream>>>(Qb, Kbuf, Vt, attn);
  gemm_out<<<dim3(DMODEL / 128, M_ROWS / 128), 256, 0, stream>>>(
      attn, WoutT, out, M_ROWS, DMODEL, DMODEL);
}

// Round 9
// 211.960 us; speedup vs baseline: 1.0852x; 1.0257x over previous
//
#include <hip/hip_runtime.h>

typedef __bf16 bf16;
typedef __bf16 bf16x4 __attribute__((ext_vector_type(4)));
typedef __bf16 bf16x8 __attribute__((ext_vector_type(8)));
typedef short s16x4 __attribute__((ext_vector_type(4)));
typedef float f32x4 __attribute__((ext_vector_type(4)));

constexpr int BATCH = 2;
constexpr int SEQ   = 2048;
constexpr int DMODEL= 1024;
constexpr int NH    = 16;
constexpr int HD    = 64;
constexpr int M_ROWS= BATCH * SEQ;      // 4096
constexpr int N_QKV = 3 * DMODEL;       // 3072

// async global->LDS, 16B per lane; LDS dest is wave-uniform base + lane*16
__device__ __forceinline__ void gl_lds16(const bf16* g, bf16* l) {
  __builtin_amdgcn_global_load_lds(
      (const __attribute__((address_space(1))) unsigned int*)g,
      (__attribute__((address_space(3))) unsigned int*)l, 16, 0, 0);
}

// K=16 bf16 MFMA: v_mfma_f32_16x16x16_bf16 (gfx90a-lineage builtin, takes
// short4).  Host pass has no amdgcn builtins -> trivial fallback there.
__device__ __forceinline__ f32x4 mfma_16x16x16_bf16(bf16x4 a, bf16x4 b,
                                                    f32x4 c) {
#if defined(__HIP_DEVICE_COMPILE__)
  union { bf16x4 h; s16x4 s; } ua{a}, ub{b};
  return __builtin_amdgcn_mfma_f32_16x16x16bf16_1k(ua.s, ub.s, c, 0, 0, 0);
#else
  return c;  // never executed; host pass only needs this to parse
#endif
}

// ---------------------------------------------------------------------------
// Transpose + cast fp32 [R][C] -> bf16 [C][R]
// ---------------------------------------------------------------------------
__global__ __launch_bounds__(256) void transpose_cast_kernel(
    const float* __restrict__ src, bf16* __restrict__ dst, int R, int C) {
  __shared__ float tile[32][33];
  const int c0 = blockIdx.x * 32, r0 = blockIdx.y * 32;
  const int tx = threadIdx.x, ty = threadIdx.y;  // blockDim = (32, 8)
#pragma unroll
  for (int i = 0; i < 4; i++)
    tile[ty + 8 * i][tx] = src[(size_t)(r0 + ty + 8 * i) * C + c0 + tx];
  __syncthreads();
#pragma unroll
  for (int i = 0; i < 4; i++)
    dst[(size_t)(c0 + ty + 8 * i) * R + r0 + tx] = (bf16)tile[tx][ty + 8 * i];
}

// ---------------------------------------------------------------------------
// Cast fp32 -> bf16 elementwise (8 elems/thread)
// ---------------------------------------------------------------------------
__global__ __launch_bounds__(256) void cast_f32_bf16(
    const float* __restrict__ src, bf16* __restrict__ dst) {
  const int i = (blockIdx.x * 256 + threadIdx.x) * 8;
  float4 f0 = *(const float4*)&src[i];
  float4 f1 = *(const float4*)&src[i + 4];
  bf16x8 v;
  v[0] = (bf16)f0.x; v[1] = (bf16)f0.y; v[2] = (bf16)f0.z; v[3] = (bf16)f0.w;
  v[4] = (bf16)f1.x; v[5] = (bf16)f1.y; v[6] = (bf16)f1.z; v[7] = (bf16)f1.w;
  *(bf16x8*)&dst[i] = v;
}

// ---------------------------------------------------------------------------
// GEMM core macro-structure (m97): 128x128 tile, BK=32, 256 threads,
// unpadded LDS + global_load_lds width 16.
// ---------------------------------------------------------------------------
#define GEMM_BODY(A, BT, K)                                                    \
  __shared__ bf16 As[128 * 32];                                                \
  __shared__ bf16 Bs[128 * 32];                                                \
  const int t = threadIdx.x;                                                   \
  const int m0 = blockIdx.y * 128;                                             \
  const int n0 = blockIdx.x * 128;                                             \
  const int w = t >> 6, lane = t & 63, g = lane >> 4, li = lane & 15;          \
  const int r0w = (w & 1) * 64, c0w = (w >> 1) * 64;                           \
  f32x4 acc[4][4] = {};                                                        \
  for (int k0 = 0; k0 < (K); k0 += 32) {                                       \
    __syncthreads();                                                           \
    _Pragma("unroll") for (int c = 0; c < 2; c++) {                            \
      const int idx = (w * 2 + c) * 64 + lane;                                 \
      const int row = idx >> 2, col = (idx & 3) * 8;                           \
      gl_lds16(&(A)[(size_t)(m0 + row) * (K) + k0 + col],                      \
               &As[(w * 2 + c) * 512]);                                        \
      gl_lds16(&(BT)[(size_t)(n0 + row) * (K) + k0 + col],                     \
               &Bs[(w * 2 + c) * 512]);                                        \
    }                                                                          \
    __syncthreads();                                                           \
    bf16x8 a[4], b[4];                                                         \
    _Pragma("unroll") for (int mt = 0; mt < 4; mt++)                           \
        a[mt] = *(const bf16x8*)&As[(r0w + mt * 16 + li) * 32 + g * 8];        \
    _Pragma("unroll") for (int nt = 0; nt < 4; nt++)                           \
        b[nt] = *(const bf16x8*)&Bs[(c0w + nt * 16 + li) * 32 + g * 8];        \
    _Pragma("unroll") for (int mt = 0; mt < 4; mt++)                           \
        _Pragma("unroll") for (int nt = 0; nt < 4; nt++)                       \
            acc[mt][nt] = __builtin_amdgcn_mfma_f32_16x16x32_bf16(             \
                a[mt], b[nt], acc[mt][nt], 0, 0, 0);                           \
  }

// ---------------------------------------------------------------------------
// Out-projection GEMM: C fp32 [M][N] = A[M][K] * BT[N][K]^T
// ---------------------------------------------------------------------------
__global__ __launch_bounds__(256) void gemm_out(
    const bf16* __restrict__ A, const bf16* __restrict__ BT,
    float* __restrict__ C, int M, int N, int K) {
  GEMM_BODY(A, BT, K)
#pragma unroll
  for (int mt = 0; mt < 4; mt++)
#pragma unroll
    for (int nt = 0; nt < 4; nt++)
#pragma unroll
      for (int r = 0; r < 4; r++) {
        const int m = m0 + r0w + mt * 16 + g * 4 + r;
        const int n = n0 + c0w + nt * 16 + li;
        C[(size_t)m * N + n] = acc[mt][nt][r];
      }
}

// ---------------------------------------------------------------------------
// QKV GEMM with fused RoPE + scatter.  Q additionally pre-scaled by
// 1/sqrt(hd)*log2(e) so flash_attn can exp2 the raw MFMA output.
// ---------------------------------------------------------------------------
__global__ __launch_bounds__(256) void gemm_qkv_rope(
    const bf16* __restrict__ A, const bf16* __restrict__ BT,
    bf16* __restrict__ Qb, bf16* __restrict__ Kb, bf16* __restrict__ Vt) {
  constexpr int K = DMODEL;
  GEMM_BODY(A, BT, K)

  const int region = n0 >> 10;               // 0=q, 1=k, 2=v
  const int b = m0 >> 11;                    // batch (block-uniform)
  const int h = ((n0 + c0w) >> 6) & 15;      // head (wave-uniform)
  const size_t bh = (size_t)(b * NH + h);

  if (region < 2) {
    bf16* dst = region == 0 ? Qb : Kb;
    const float outsc = region == 0 ? 0.125f * 1.44269504f : 1.f;
    const float L = 13.287712379549449f;  // log2(10000)
    const float if0 = exp2f(-(float)(2 * li) / 64.f * L);
    const float if1 = exp2f(-(float)(2 * (li + 16)) / 64.f * L);
#pragma unroll
    for (int mt = 0; mt < 4; mt++)
#pragma unroll
      for (int r = 0; r < 4; r++) {
        const int s = (m0 + r0w + mt * 16 + g * 4 + r) & (SEQ - 1);
        float cs[2], sn[2];
        __sincosf((float)s * if0, &sn[0], &cs[0]);
        __sincosf((float)s * if1, &sn[1], &cs[1]);
#pragma unroll
        for (int nt = 0; nt < 4; nt++) {
          const int d = nt * 16 + li;
          const int par = nt & 1;
          const float a = acc[mt][nt][r];
          const float ap = acc[mt][nt ^ 2][r];
          const float v = (nt < 2) ? a * cs[par] - ap * sn[par]
                                   : a * cs[par] + ap * sn[par];
          dst[(bh * SEQ + s) * HD + d] = (bf16)(v * outsc);
        }
      }
  } else {
    // V: transpose-scatter, pack 4 consecutive s per store
#pragma unroll
    for (int mt = 0; mt < 4; mt++)
#pragma unroll
      for (int nt = 0; nt < 4; nt++) {
        const int s = (m0 + r0w + mt * 16 + g * 4) & (SEQ - 1);
        const int d = nt * 16 + li;
        bf16x4 v;
#pragma unroll
        for (int r = 0; r < 4; r++) v[r] = (bf16)acc[mt][nt][r];
        *(bf16x4*)&Vt[(bh * HD + d) * SEQ + s] = v;
      }
  }
}

// ---------------------------------------------------------------------------
// Flash attention v8 (causal): BQ=64, BK=64, 4 waves x 16 q-rows, 256 thr.
// Heavy-first 1024-block grid (qt = 31 - bx/32): HW backfill keeps ~4
// blocks/CU (16 waves) resident for uniform concurrency — fixes the v7
// light-block-drains-first occupancy collapse.
// S^T trick (P in registers), ones-row MFMA for l, exp2 domain (Q
// pre-scaled), K/V double-buffered via global_load_lds + XOR swizzle.
// LDS = 32 KB/block -> 4 blocks/CU.
// ---------------------------------------------------------------------------
__global__ __launch_bounds__(256, 4) void flash_attn8(
    const bf16* __restrict__ Q, const bf16* __restrict__ Kb,
    const bf16* __restrict__ Vt, bf16* __restrict__ Oout) {
  const int bx = blockIdx.x;         // 0..1023
  const int qt = 31 - (bx >> 5);     // heavy tiles dispatched first
  const int bh = bx & 31;
  const int q0 = qt * 64;
  const int t = threadIdx.x, w = t >> 6, lane = t & 63, g = lane >> 4,
            li = lane & 15;

  // 64x64 tiles as 512 chunks of 8 bf16; chunk p holds row p>>3,
  // source col group (p&7)^(row&7)  (XOR swizzle -> conflict-free reads)
  __shared__ bf16 Ks[2][4096];
  __shared__ bf16 Vs[2][4096];

  const bf16* Qh = Q  + (size_t)bh * SEQ * HD;
  const bf16* Kh = Kb + (size_t)bh * SEQ * HD;
  const bf16* Vh = Vt + (size_t)bh * HD * SEQ;

  const int qw = q0 + w * 16;        // this wave's 16 q-rows (q = qw + li)

  bf16x8 qf[2];
#pragma unroll
  for (int ks = 0; ks < 2; ks++)
    qf[ks] = *(const bf16x8*)&Qh[(size_t)(qw + li) * HD + ks * 32 + g * 8];

  f32x4 o[4] = {};   // O^T[dv = dt*16 + g*4 + r][q = li]
  f32x4 o4  = {};    // ones-row accumulator: every element ends = l(q=li)
  bf16x4 ones;
#pragma unroll
  for (int r = 0; r < 4; r++) ones[r] = (bf16)1.f;

  // staging: wave supplies chunks w*128 + c*64 + lane (c = 0,1) per tile
  const int p0 = w * 128 + lane, p1 = p0 + 64;
  const int sr0 = p0 >> 3, sc0 = ((p0 & 7) ^ (sr0 & 7)) * 8;
  const int sr1 = p1 >> 3, sc1 = ((p1 & 7) ^ (sr1 & 7)) * 8;
  const int lo0 = w * 1024, lo1 = w * 1024 + 512;  // element offsets

  const int jend = q0 + 64;

  // prologue: stage tile j=0 -> buf0
  gl_lds16(&Kh[(size_t)sr0 * HD + sc0], &Ks[0][lo0]);
  gl_lds16(&Kh[(size_t)sr1 * HD + sc1], &Ks[0][lo1]);
  gl_lds16(&Vh[(size_t)sr0 * SEQ + sc0], &Vs[0][lo0]);
  gl_lds16(&Vh[(size_t)sr1 * SEQ + sc1], &Vs[0][lo1]);
  __syncthreads();

  for (int j0 = 0; j0 < jend; j0 += 64) {
    const int cur = (j0 >> 6) & 1, nxt = cur ^ 1;
    if (j0 + 64 < jend) {
      const int jn = j0 + 64;
      gl_lds16(&Kh[(size_t)(jn + sr0) * HD + sc0], &Ks[nxt][lo0]);
      gl_lds16(&Kh[(size_t)(jn + sr1) * HD + sc1], &Ks[nxt][lo1]);
      gl_lds16(&Vh[(size_t)sr0 * SEQ + jn + sc0], &Vs[nxt][lo0]);
      gl_lds16(&Vh[(size_t)sr1 * SEQ + jn + sc1], &Vs[nxt][lo1]);
    }

    if (j0 <= qw + 15) {  // wave-uniform: skip fully-masked tiles
      const bool masked = (j0 + 63 > qw);
      const int ntlim = min(4, ((qw + 15 - j0) >> 4) + 1);

      // ---- S^T = K Q^T ----
      f32x4 sacc[4] = {};
#pragma unroll
      for (int ks = 0; ks < 2; ks++)
#pragma unroll
        for (int nt = 0; nt < 4; nt++) {
          if (nt >= ntlim) continue;
          const int rK = nt * 16 + li;
          const int pK = rK * 8 + ((ks * 4 + g) ^ (li & 7));
          bf16x8 kf = *(const bf16x8*)&Ks[cur][pK * 8];
          sacc[nt] = __builtin_amdgcn_mfma_f32_16x16x32_bf16(kf, qf[ks],
                                                             sacc[nt], 0, 0, 0);
        }

      // ---- P^T = 2^(S^T) (+mask on diagonal strips) in registers ----
      bf16x4 pf[4];
#pragma unroll
      for (int nt = 0; nt < 4; nt++) {
        if (nt >= ntlim) continue;
#pragma unroll
        for (int r = 0; r < 4; r++) {
          float v = sacc[nt][r];
          if (masked) {
            const int kk = j0 + nt * 16 + g * 4 + r;
            v = (kk <= qw + li) ? v : -1e30f;
          }
          pf[nt][r] = (bf16)exp2f(v);
        }
      }

      // ---- O^T += V^T P^T ; l via ones-row MFMA ----
#pragma unroll
      for (int nt = 0; nt < 4; nt++) {
        if (nt >= ntlim) continue;
        o4 = mfma_16x16x16_bf16(ones, pf[nt], o4);
#pragma unroll
        for (int dt = 0; dt < 4; dt++) {
          const int rV = dt * 16 + li;
          const int cg = nt * 2 + (g >> 1);
          const int pV = rV * 8 + (cg ^ (rV & 7));
          bf16x4 vfrag = *(const bf16x4*)&Vs[cur][pV * 8 + (g & 1) * 4];
          o[dt] = mfma_16x16x16_bf16(vfrag, pf[nt], o[dt]);
        }
      }
    }
    __syncthreads();  // drains next-tile DMA; fences cur-buf reuse
  }

  const float inv_l = 1.f / o4[0];   // all 4 regs equal l(q=li)

  // ---- epilogue: O^T -> attn[b*S+s][h*64+dv], 4x bf16x4 stores ----
  const int b = bh >> 4, h = bh & 15;
  const int s = qw + li;
#pragma unroll
  for (int dt = 0; dt < 4; dt++) {
    bf16x4 ov;
#pragma unroll
    for (int r = 0; r < 4; r++) ov[r] = (bf16)(o[dt][r] * inv_l);
    *(bf16x4*)&Oout[((size_t)(b * SEQ + s)) * DMODEL + h * 64 + dt * 16 +
                    g * 4] = ov;
  }
}

// ---------------------------------------------------------------------------
// Launch
// ---------------------------------------------------------------------------
extern "C" void kernel_launch(void* const* d_in, const int* in_sizes, int n_in,
                              void* d_out, int out_size, void* d_ws,
                              size_t ws_size, hipStream_t stream) {
  const float* x     = (const float*)d_in[0];
  // d_in[1] = causal mask (int32) — causality implemented directly
  const float* w_qkv = (const float*)d_in[2];
  const float* w_out = (const float*)d_in[3];
  float* out = (float*)d_out;

  char* ws = (char*)d_ws;
  bf16* WqkvT = (bf16*)(ws);                        //  6,291,456 B
  bf16* WoutT = (bf16*)(ws + 6291456);              //  2,097,152 B
  bf16* xb    = (bf16*)(ws + 8388608);              //  8,388,608 B
  bf16* Qb    = (bf16*)(ws + 16777216);             //  8,388,608 B
  bf16* Kbuf  = (bf16*)(ws + 25165824);             //  8,388,608 B
  bf16* Vt    = (bf16*)(ws + 33554432);             //  8,388,608 B
  bf16* attn  = (bf16*)(ws + 41943040);             //  8,388,608 B (end ~48MB)

  cast_f32_bf16<<<M_ROWS * DMODEL / 2048, 256, 0, stream>>>(x, xb);
  transpose_cast_kernel<<<dim3(N_QKV / 32, DMODEL / 32), dim3(32, 8), 0,
                          stream>>>(w_qkv, WqkvT, DMODEL, N_QKV);
  transpose_cast_kernel<<<dim3(DMODEL / 32, DMODEL / 32), dim3(32, 8), 0,
                          stream>>>(w_out, WoutT, DMODEL, DMODEL);
  gemm_qkv_rope<<<dim3(N_QKV / 128, M_ROWS / 128), 256, 0, stream>>>(
      xb, WqkvT, Qb, Kbuf, Vt);
  flash_attn8<<<dim3(1024), 256, 0, stream>>>(Qb, Kbuf, Vt, attn);
  gemm_out<<<dim3(DMODEL / 128, M_ROWS / 128), 256, 0, stream>>>(
      attn, WoutT, out, M_ROWS, DMODEL, DMODEL);
}